// Round 1
// baseline (1371.983 us; speedup 1.0000x reference)
//
#include <hip/hip_runtime.h>

#define K_DIM 256
#define OD 128

// ---------------- GEMM: pre = x @ W  (f32, M x 256 @ 256 x 128) ----------------
// Block tile: 64 rows x 128 cols, 256 threads, each thread 8x4 register tile.
__global__ __launch_bounds__(256) void gemm_f32(const float* __restrict__ x,
                                                const float* __restrict__ W,
                                                float* __restrict__ pre, int M) {
    __shared__ float xs[64][64];    // [row][k]
    __shared__ float ws[64][128];   // [k][col]
    const int t  = threadIdx.x;
    const int tx = t & 31;          // col group: cols tx*4 .. tx*4+3
    const int ty = t >> 5;          // row group: rows ty*8 .. ty*8+7
    const int row0 = blockIdx.x * 64;
    float acc[8][4] = {};
    for (int k0 = 0; k0 < K_DIM; k0 += 64) {
        // stage x tile: 64 rows x 64 k = 1024 float4, 4 per thread
        #pragma unroll
        for (int i = 0; i < 4; ++i) {
            int f4 = t + i * 256;
            int r  = f4 >> 4;
            int kk = (f4 & 15) << 2;
            int grow = row0 + r;
            float4 v = make_float4(0.f, 0.f, 0.f, 0.f);
            if (grow < M)
                v = *reinterpret_cast<const float4*>(x + (size_t)grow * K_DIM + k0 + kk);
            *reinterpret_cast<float4*>(&xs[r][kk]) = v;
        }
        // stage W tile: 64 k x 128 cols = 2048 float4, 8 per thread
        #pragma unroll
        for (int i = 0; i < 8; ++i) {
            int f4 = t + i * 256;
            int kk = f4 >> 5;
            int c  = (f4 & 31) << 2;
            *reinterpret_cast<float4*>(&ws[kk][c]) =
                *reinterpret_cast<const float4*>(W + (size_t)(k0 + kk) * OD + c);
        }
        __syncthreads();
        #pragma unroll
        for (int kk = 0; kk < 64; ++kk) {
            float4 wv = *reinterpret_cast<const float4*>(&ws[kk][tx << 2]);
            #pragma unroll
            for (int i = 0; i < 8; ++i) {
                float xv = xs[ty * 8 + i][kk];
                acc[i][0] = fmaf(xv, wv.x, acc[i][0]);
                acc[i][1] = fmaf(xv, wv.y, acc[i][1]);
                acc[i][2] = fmaf(xv, wv.z, acc[i][2]);
                acc[i][3] = fmaf(xv, wv.w, acc[i][3]);
            }
        }
        __syncthreads();
    }
    #pragma unroll
    for (int i = 0; i < 8; ++i) {
        int grow = row0 + ty * 8 + i;
        if (grow < M)
            *reinterpret_cast<float4*>(pre + (size_t)grow * OD + (tx << 2)) =
                make_float4(acc[i][0], acc[i][1], acc[i][2], acc[i][3]);
    }
}

// ---------------- SpMM scatter: out[row] += val * pre[col] ----------------
// One wave (64 lanes) per edge; each lane handles 2 of the 128 output cols.
__global__ __launch_bounds__(256) void spmm_scatter(const int* __restrict__ rows,
                                                    const int* __restrict__ cols,
                                                    const float* __restrict__ vals,
                                                    const float* __restrict__ pre,
                                                    float* __restrict__ out, int E) {
    const int e    = (int)((blockIdx.x * (unsigned)blockDim.x + threadIdx.x) >> 6);
    const int lane = threadIdx.x & 63;
    if (e >= E) return;
    const int   r = rows[e];
    const int   c = cols[e];
    const float v = vals[e];
    const float2 p = *reinterpret_cast<const float2*>(pre + (size_t)c * OD + lane * 2);
    float* o = out + (size_t)r * OD + lane * 2;
    unsafeAtomicAdd(o,     v * p.x);   // hardware global_atomic_add_f32
    unsafeAtomicAdd(o + 1, v * p.y);
}

// ---------------- finalize: out = relu(out + b) ----------------
__global__ __launch_bounds__(256) void bias_relu(float* __restrict__ out,
                                                 const float* __restrict__ b, int n4) {
    int i = blockIdx.x * 256 + threadIdx.x;
    if (i >= n4) return;
    float4 v = reinterpret_cast<float4*>(out)[i];
    int c = (i & ((OD / 4) - 1)) << 2;   // column of first element
    float4 bv = *reinterpret_cast<const float4*>(b + c);
    v.x = fmaxf(v.x + bv.x, 0.f);
    v.y = fmaxf(v.y + bv.y, 0.f);
    v.z = fmaxf(v.z + bv.z, 0.f);
    v.w = fmaxf(v.w + bv.w, 0.f);
    reinterpret_cast<float4*>(out)[i] = v;
}

extern "C" void kernel_launch(void* const* d_in, const int* in_sizes, int n_in,
                              void* d_out, int out_size, void* d_ws, size_t ws_size,
                              hipStream_t stream) {
    const float* x     = (const float*)d_in[0];
    const int*   erows = (const int*)d_in[1];
    const int*   ecols = (const int*)d_in[2];
    const float* evals = (const float*)d_in[3];
    const float* W     = (const float*)d_in[4];
    const float* b     = (const float*)d_in[5];
    float*       out   = (float*)d_out;
    float*       pre   = (float*)d_ws;           // 50000*128 f32 = 25.6 MB scratch

    const int M = in_sizes[0] / K_DIM;           // 50000 nodes
    const int E = in_sizes[1];                   // 1.6M edges

    // zero the accumulator (harness does not re-poison/zero between replays)
    hipMemsetAsync(d_out, 0, (size_t)out_size * sizeof(float), stream);

    gemm_f32<<<(M + 63) / 64, 256, 0, stream>>>(x, W, pre, M);

    // one wave per edge -> 4 edges per 256-thread block
    spmm_scatter<<<(E + 3) / 4, 256, 0, stream>>>(erows, ecols, evals, pre, out, E);

    bias_relu<<<(out_size / 4 + 255) / 256, 256, 0, stream>>>(out, b, out_size / 4);
}

// Round 2
// 460.683 us; speedup vs baseline: 2.9782x; 2.9782x over previous
//
#include <hip/hip_runtime.h>

#define K_DIM 256
#define OD 128

// ---------------- GEMM: pre = x @ W  (f32, M x 256 @ 256 x 128) ----------------
__global__ __launch_bounds__(256) void gemm_f32(const float* __restrict__ x,
                                                const float* __restrict__ W,
                                                float* __restrict__ pre, int M) {
    __shared__ float xs[64][64];    // [row][k]
    __shared__ float ws[64][128];   // [k][col]
    const int t  = threadIdx.x;
    const int tx = t & 31;
    const int ty = t >> 5;
    const int row0 = blockIdx.x * 64;
    float acc[8][4] = {};
    for (int k0 = 0; k0 < K_DIM; k0 += 64) {
        #pragma unroll
        for (int i = 0; i < 4; ++i) {
            int f4 = t + i * 256;
            int r  = f4 >> 4;
            int kk = (f4 & 15) << 2;
            int grow = row0 + r;
            float4 v = make_float4(0.f, 0.f, 0.f, 0.f);
            if (grow < M)
                v = *reinterpret_cast<const float4*>(x + (size_t)grow * K_DIM + k0 + kk);
            *reinterpret_cast<float4*>(&xs[r][kk]) = v;
        }
        #pragma unroll
        for (int i = 0; i < 8; ++i) {
            int f4 = t + i * 256;
            int kk = f4 >> 5;
            int c  = (f4 & 31) << 2;
            *reinterpret_cast<float4*>(&ws[kk][c]) =
                *reinterpret_cast<const float4*>(W + (size_t)(k0 + kk) * OD + c);
        }
        __syncthreads();
        #pragma unroll
        for (int kk = 0; kk < 64; ++kk) {
            float4 wv = *reinterpret_cast<const float4*>(&ws[kk][tx << 2]);
            #pragma unroll
            for (int i = 0; i < 8; ++i) {
                float xv = xs[ty * 8 + i][kk];
                acc[i][0] = fmaf(xv, wv.x, acc[i][0]);
                acc[i][1] = fmaf(xv, wv.y, acc[i][1]);
                acc[i][2] = fmaf(xv, wv.z, acc[i][2]);
                acc[i][3] = fmaf(xv, wv.w, acc[i][3]);
            }
        }
        __syncthreads();
    }
    #pragma unroll
    for (int i = 0; i < 8; ++i) {
        int grow = row0 + ty * 8 + i;
        if (grow < M)
            *reinterpret_cast<float4*>(pre + (size_t)grow * OD + (tx << 2)) =
                make_float4(acc[i][0], acc[i][1], acc[i][2], acc[i][3]);
    }
}

// ---------------- CSR build ----------------
__global__ __launch_bounds__(256) void histogram_rows(const int* __restrict__ rows,
                                                      int* __restrict__ cnt, int E) {
    int i = blockIdx.x * 256 + threadIdx.x;
    if (i < E) atomicAdd(&cnt[rows[i]], 1);
}

// Single-workgroup exclusive scan of cnt[0..n) -> row_ptr[0..n] and cursor[0..n)
__global__ __launch_bounds__(1024) void scan_rowptr(const int* __restrict__ cnt,
                                                    int* __restrict__ row_ptr,
                                                    int* __restrict__ cursor, int n) {
    __shared__ int buf[1024];
    __shared__ int carry;
    if (threadIdx.x == 0) carry = 0;
    __syncthreads();
    for (int base = 0; base < n; base += 1024) {
        int i = base + (int)threadIdx.x;
        int v = (i < n) ? cnt[i] : 0;
        buf[threadIdx.x] = v;
        __syncthreads();
        #pragma unroll
        for (int off = 1; off < 1024; off <<= 1) {
            int t = (threadIdx.x >= (unsigned)off) ? buf[threadIdx.x - off] : 0;
            __syncthreads();
            buf[threadIdx.x] += t;
            __syncthreads();
        }
        int excl = buf[threadIdx.x] - v;
        if (i < n) {
            int p = carry + excl;
            row_ptr[i] = p;
            cursor[i]  = p;
        }
        __syncthreads();
        if (threadIdx.x == 1023) carry += buf[1023];
        __syncthreads();
    }
    if (threadIdx.x == 0) row_ptr[n] = carry;
}

__global__ __launch_bounds__(256) void fill_csr(const int* __restrict__ rows,
                                                const int* __restrict__ cols,
                                                const float* __restrict__ vals,
                                                int* __restrict__ cursor,
                                                int* __restrict__ csr_col,
                                                float* __restrict__ csr_val, int E) {
    int i = blockIdx.x * 256 + threadIdx.x;
    if (i >= E) return;
    int pos = atomicAdd(&cursor[rows[i]], 1);
    csr_col[pos] = cols[i];
    csr_val[pos] = vals[i];
}

// ---------------- gather: out[r] = relu(b + sum val*pre[col]) ----------------
// One wave per row; lane handles 2 of 128 cols (float2 = 8B/lane, 512B/wave/edge).
__global__ __launch_bounds__(256) void spmm_gather(const int* __restrict__ row_ptr,
                                                   const int* __restrict__ csr_col,
                                                   const float* __restrict__ csr_val,
                                                   const float* __restrict__ pre,
                                                   const float* __restrict__ b,
                                                   float* __restrict__ out, int n) {
    const int w    = (int)((blockIdx.x * 256u + threadIdx.x) >> 6);
    const int lane = threadIdx.x & 63;
    if (w >= n) return;
    const int beg = row_ptr[w];
    const int end = row_ptr[w + 1];
    float ax = 0.f, ay = 0.f;
    int j = beg;
    // 4-edge unroll: independent (col,val) + gather loads per step
    for (; j + 4 <= end; j += 4) {
        int   c0 = csr_col[j],     c1 = csr_col[j + 1];
        int   c2 = csr_col[j + 2], c3 = csr_col[j + 3];
        float v0 = csr_val[j],     v1 = csr_val[j + 1];
        float v2 = csr_val[j + 2], v3 = csr_val[j + 3];
        float2 p0 = *reinterpret_cast<const float2*>(pre + (size_t)c0 * OD + lane * 2);
        float2 p1 = *reinterpret_cast<const float2*>(pre + (size_t)c1 * OD + lane * 2);
        float2 p2 = *reinterpret_cast<const float2*>(pre + (size_t)c2 * OD + lane * 2);
        float2 p3 = *reinterpret_cast<const float2*>(pre + (size_t)c3 * OD + lane * 2);
        ax = fmaf(v0, p0.x, ax); ay = fmaf(v0, p0.y, ay);
        ax = fmaf(v1, p1.x, ax); ay = fmaf(v1, p1.y, ay);
        ax = fmaf(v2, p2.x, ax); ay = fmaf(v2, p2.y, ay);
        ax = fmaf(v3, p3.x, ax); ay = fmaf(v3, p3.y, ay);
    }
    for (; j < end; ++j) {
        int   c = csr_col[j];
        float v = csr_val[j];
        float2 p = *reinterpret_cast<const float2*>(pre + (size_t)c * OD + lane * 2);
        ax = fmaf(v, p.x, ax); ay = fmaf(v, p.y, ay);
    }
    float2 bv = *reinterpret_cast<const float2*>(b + lane * 2);
    float2 o;
    o.x = fmaxf(ax + bv.x, 0.f);
    o.y = fmaxf(ay + bv.y, 0.f);
    *reinterpret_cast<float2*>(out + (size_t)w * OD + lane * 2) = o;
}

// ---------------- fallback (tiny ws): original atomic scatter ----------------
__global__ __launch_bounds__(256) void spmm_scatter(const int* __restrict__ rows,
                                                    const int* __restrict__ cols,
                                                    const float* __restrict__ vals,
                                                    const float* __restrict__ pre,
                                                    float* __restrict__ out, int E) {
    const int e    = (int)((blockIdx.x * 256u + threadIdx.x) >> 6);
    const int lane = threadIdx.x & 63;
    if (e >= E) return;
    const int   r = rows[e];
    const int   c = cols[e];
    const float v = vals[e];
    const float2 p = *reinterpret_cast<const float2*>(pre + (size_t)c * OD + lane * 2);
    float* o = out + (size_t)r * OD + lane * 2;
    unsafeAtomicAdd(o,     v * p.x);
    unsafeAtomicAdd(o + 1, v * p.y);
}

__global__ __launch_bounds__(256) void bias_relu(float* __restrict__ out,
                                                 const float* __restrict__ b, int n4) {
    int i = blockIdx.x * 256 + threadIdx.x;
    if (i >= n4) return;
    float4 v = reinterpret_cast<float4*>(out)[i];
    int c = (i & ((OD / 4) - 1)) << 2;
    float4 bv = *reinterpret_cast<const float4*>(b + c);
    v.x = fmaxf(v.x + bv.x, 0.f);
    v.y = fmaxf(v.y + bv.y, 0.f);
    v.z = fmaxf(v.z + bv.z, 0.f);
    v.w = fmaxf(v.w + bv.w, 0.f);
    reinterpret_cast<float4*>(out)[i] = v;
}

extern "C" void kernel_launch(void* const* d_in, const int* in_sizes, int n_in,
                              void* d_out, int out_size, void* d_ws, size_t ws_size,
                              hipStream_t stream) {
    const float* x     = (const float*)d_in[0];
    const int*   erows = (const int*)d_in[1];
    const int*   ecols = (const int*)d_in[2];
    const float* evals = (const float*)d_in[3];
    const float* W     = (const float*)d_in[4];
    const float* b     = (const float*)d_in[5];
    float*       out   = (float*)d_out;

    const int M = in_sizes[0] / K_DIM;           // 50000 nodes
    const int E = in_sizes[1];                   // 1.6M edges

    // workspace layout (16B-aligned)
    char* ws = (char*)d_ws;
    size_t off = 0;
    auto alloc = [&](size_t bytes) { char* p = ws + off; off = (off + bytes + 15) & ~(size_t)15; return p; };
    float* pre     = (float*)alloc((size_t)M * OD * sizeof(float));   // 25.6 MB
    int*   cnt     = (int*)  alloc((size_t)M * sizeof(int));
    int*   row_ptr = (int*)  alloc((size_t)(M + 1) * sizeof(int));
    int*   cursor  = (int*)  alloc((size_t)M * sizeof(int));
    int*   csr_col = (int*)  alloc((size_t)E * sizeof(int));
    float* csr_val = (float*)alloc((size_t)E * sizeof(float));
    const bool csr_ok = off <= ws_size;

    gemm_f32<<<(M + 63) / 64, 256, 0, stream>>>(x, W, pre, M);

    if (csr_ok) {
        hipMemsetAsync(cnt, 0, (size_t)M * sizeof(int), stream);
        histogram_rows<<<(E + 255) / 256, 256, 0, stream>>>(erows, cnt, E);
        scan_rowptr<<<1, 1024, 0, stream>>>(cnt, row_ptr, cursor, M);
        fill_csr<<<(E + 255) / 256, 256, 0, stream>>>(erows, ecols, evals, cursor,
                                                      csr_col, csr_val, E);
        spmm_gather<<<(M * 64 + 255) / 256, 256, 0, stream>>>(row_ptr, csr_col, csr_val,
                                                              pre, b, out, M);
    } else {
        hipMemsetAsync(d_out, 0, (size_t)out_size * sizeof(float), stream);
        spmm_scatter<<<(E + 3) / 4, 256, 0, stream>>>(erows, ecols, evals, pre, out, E);
        bias_relu<<<(out_size / 4 + 255) / 256, 256, 0, stream>>>(out, b, out_size / 4);
    }
}

// Round 3
// 305.137 us; speedup vs baseline: 4.4963x; 1.5098x over previous
//
#include <hip/hip_runtime.h>

#define K_DIM 256
#define OD 128

__device__ inline unsigned short f2bf(float f) {
    unsigned u = __float_as_uint(f);
    unsigned r = (u + 0x7fffu + ((u >> 16) & 1u)) >> 16;   // round-to-nearest-even
    return (unsigned short)r;
}

// ---------------- fused: GEMM (pre_bf16 = bf16(x @ W)) + row histogram ----------------
// Blocks [0, nGemm): 64-row GEMM tiles. Blocks [nGemm, grid): grid-stride histogram.
__global__ __launch_bounds__(256) void gemm_hist(const float* __restrict__ x,
                                                 const float* __restrict__ W,
                                                 unsigned short* __restrict__ preb,
                                                 const int* __restrict__ rows,
                                                 int* __restrict__ cnt,
                                                 int M, int E, int nGemm) {
    __shared__ float xs[64][64];    // [row][k]
    __shared__ float ws[64][128];   // [k][col]
    if ((int)blockIdx.x >= nGemm) {
        // histogram branch
        int nb  = gridDim.x - nGemm;
        int bid = blockIdx.x - nGemm;
        for (int i = bid * 256 + (int)threadIdx.x; i < E; i += nb * 256)
            atomicAdd(&cnt[rows[i]], 1);
        return;
    }
    const int t  = threadIdx.x;
    const int tx = t & 31;
    const int ty = t >> 5;
    const int row0 = blockIdx.x * 64;
    float acc[8][4] = {};
    for (int k0 = 0; k0 < K_DIM; k0 += 64) {
        #pragma unroll
        for (int i = 0; i < 4; ++i) {
            int f4 = t + i * 256;
            int r  = f4 >> 4;
            int kk = (f4 & 15) << 2;
            int grow = row0 + r;
            float4 v = make_float4(0.f, 0.f, 0.f, 0.f);
            if (grow < M)
                v = *reinterpret_cast<const float4*>(x + (size_t)grow * K_DIM + k0 + kk);
            *reinterpret_cast<float4*>(&xs[r][kk]) = v;
        }
        #pragma unroll
        for (int i = 0; i < 8; ++i) {
            int f4 = t + i * 256;
            int kk = f4 >> 5;
            int c  = (f4 & 31) << 2;
            *reinterpret_cast<float4*>(&ws[kk][c]) =
                *reinterpret_cast<const float4*>(W + (size_t)(k0 + kk) * OD + c);
        }
        __syncthreads();
        #pragma unroll
        for (int kk = 0; kk < 64; ++kk) {
            float4 wv = *reinterpret_cast<const float4*>(&ws[kk][tx << 2]);
            #pragma unroll
            for (int i = 0; i < 8; ++i) {
                float xv = xs[ty * 8 + i][kk];
                acc[i][0] = fmaf(xv, wv.x, acc[i][0]);
                acc[i][1] = fmaf(xv, wv.y, acc[i][1]);
                acc[i][2] = fmaf(xv, wv.z, acc[i][2]);
                acc[i][3] = fmaf(xv, wv.w, acc[i][3]);
            }
        }
        __syncthreads();
    }
    #pragma unroll
    for (int i = 0; i < 8; ++i) {
        int grow = row0 + ty * 8 + i;
        if (grow < M) {
            unsigned lo = (unsigned)f2bf(acc[i][0]) | ((unsigned)f2bf(acc[i][1]) << 16);
            unsigned hi = (unsigned)f2bf(acc[i][2]) | ((unsigned)f2bf(acc[i][3]) << 16);
            *reinterpret_cast<uint2*>(preb + (size_t)grow * OD + (tx << 2)) =
                make_uint2(lo, hi);
        }
    }
}

// ---------------- scan: row_ptr/cursor = exclusive_scan(cnt), single WG, int4+shfl ----------------
__global__ __launch_bounds__(1024) void scan_rowptr(const int* __restrict__ cnt,
                                                    int* __restrict__ row_ptr,
                                                    int* __restrict__ cursor, int n) {
    __shared__ int wsum[16];
    __shared__ int carry_s;
    const int t = threadIdx.x, lane = t & 63, wid = t >> 6;
    if (t == 0) carry_s = 0;
    __syncthreads();
    for (int base = 0; base < n; base += 4096) {
        int i0 = base + t * 4;
        int v0 = 0, v1 = 0, v2 = 0, v3 = 0;
        if (i0 + 3 < n) {
            int4 v = *reinterpret_cast<const int4*>(cnt + i0);
            v0 = v.x; v1 = v.y; v2 = v.z; v3 = v.w;
        } else {
            if (i0     < n) v0 = cnt[i0];
            if (i0 + 1 < n) v1 = cnt[i0 + 1];
            if (i0 + 2 < n) v2 = cnt[i0 + 2];
            if (i0 + 3 < n) v3 = cnt[i0 + 3];
        }
        int s  = v0 + v1 + v2 + v3;
        int sc = s;                         // inclusive wave scan
        #pragma unroll
        for (int off = 1; off < 64; off <<= 1) {
            int u = __shfl_up(sc, off, 64);
            if (lane >= off) sc += u;
        }
        if (lane == 63) wsum[wid] = sc;
        __syncthreads();
        if (wid == 0) {
            int wv  = (lane < 16) ? wsum[lane] : 0;
            int wsc = wv;
            #pragma unroll
            for (int off = 1; off < 16; off <<= 1) {
                int u = __shfl_up(wsc, off, 64);
                if (lane >= off) wsc += u;
            }
            if (lane < 16) wsum[lane] = wsc - wv;   // exclusive wave offsets
        }
        __syncthreads();
        int excl = carry_s + wsum[wid] + (sc - s);
        int p0 = excl, p1 = p0 + v0, p2 = p1 + v1, p3 = p2 + v2;
        if (i0 + 3 < n) {
            *reinterpret_cast<int4*>(row_ptr + i0) = make_int4(p0, p1, p2, p3);
            *reinterpret_cast<int4*>(cursor  + i0) = make_int4(p0, p1, p2, p3);
        } else {
            if (i0     < n) { row_ptr[i0]     = p0; cursor[i0]     = p0; }
            if (i0 + 1 < n) { row_ptr[i0 + 1] = p1; cursor[i0 + 1] = p1; }
            if (i0 + 2 < n) { row_ptr[i0 + 2] = p2; cursor[i0 + 2] = p2; }
            if (i0 + 3 < n) { row_ptr[i0 + 3] = p3; cursor[i0 + 3] = p3; }
        }
        __syncthreads();
        if (t == 1023) carry_s += wsum[15] + sc;
        __syncthreads();
    }
    if (t == 0) row_ptr[n] = carry_s;
}

// ---------------- fill: csr[pos] = {col, val_bits}, single 8B store per edge ----------------
__global__ __launch_bounds__(256) void fill_csr(const int* __restrict__ rows,
                                                const int* __restrict__ cols,
                                                const float* __restrict__ vals,
                                                int* __restrict__ cursor,
                                                int2* __restrict__ csr, int E) {
    int i = blockIdx.x * 256 + threadIdx.x;
    if (i >= E) return;
    int pos = atomicAdd(&cursor[rows[i]], 1);
    csr[pos] = make_int2(cols[i], __float_as_int(vals[i]));
}

// ---------------- gather: out[r] = relu(b + sum val * pre_bf16[col]) ----------------
// One wave per row; lane handles cols {2*lane, 2*lane+1} via one bf16x2 (4B) load per edge.
__global__ __launch_bounds__(256) void spmm_gather(const int* __restrict__ row_ptr,
                                                   const int2* __restrict__ csr,
                                                   const unsigned* __restrict__ preb2,
                                                   const float* __restrict__ b,
                                                   float* __restrict__ out, int n) {
    const int w    = (int)((blockIdx.x * 256u + threadIdx.x) >> 6);
    const int lane = threadIdx.x & 63;
    if (w >= n) return;
    const int beg = row_ptr[w];
    const int end = row_ptr[w + 1];
    float ax = 0.f, ay = 0.f;
    int j = beg;
    for (; j + 4 <= end; j += 4) {
        int2 e0 = csr[j], e1 = csr[j + 1], e2 = csr[j + 2], e3 = csr[j + 3];
        unsigned p0 = preb2[(size_t)e0.x * (OD / 2) + lane];
        unsigned p1 = preb2[(size_t)e1.x * (OD / 2) + lane];
        unsigned p2 = preb2[(size_t)e2.x * (OD / 2) + lane];
        unsigned p3 = preb2[(size_t)e3.x * (OD / 2) + lane];
        float v0 = __int_as_float(e0.y), v1 = __int_as_float(e1.y);
        float v2 = __int_as_float(e2.y), v3 = __int_as_float(e3.y);
        ax = fmaf(v0, __uint_as_float(p0 << 16), ax);
        ay = fmaf(v0, __uint_as_float(p0 & 0xffff0000u), ay);
        ax = fmaf(v1, __uint_as_float(p1 << 16), ax);
        ay = fmaf(v1, __uint_as_float(p1 & 0xffff0000u), ay);
        ax = fmaf(v2, __uint_as_float(p2 << 16), ax);
        ay = fmaf(v2, __uint_as_float(p2 & 0xffff0000u), ay);
        ax = fmaf(v3, __uint_as_float(p3 << 16), ax);
        ay = fmaf(v3, __uint_as_float(p3 & 0xffff0000u), ay);
    }
    for (; j < end; ++j) {
        int2 e = csr[j];
        unsigned p = preb2[(size_t)e.x * (OD / 2) + lane];
        float v = __int_as_float(e.y);
        ax = fmaf(v, __uint_as_float(p << 16), ax);
        ay = fmaf(v, __uint_as_float(p & 0xffff0000u), ay);
    }
    float2 bv = *reinterpret_cast<const float2*>(b + lane * 2);
    float2 o;
    o.x = fmaxf(ax + bv.x, 0.f);
    o.y = fmaxf(ay + bv.y, 0.f);
    *reinterpret_cast<float2*>(out + (size_t)w * OD + lane * 2) = o;
}

// ---------------- fallback (tiny ws): atomic scatter over bf16 pre ----------------
__global__ __launch_bounds__(256) void spmm_scatter(const int* __restrict__ rows,
                                                    const int* __restrict__ cols,
                                                    const float* __restrict__ vals,
                                                    const unsigned* __restrict__ preb2,
                                                    float* __restrict__ out, int E) {
    const int e    = (int)((blockIdx.x * 256u + threadIdx.x) >> 6);
    const int lane = threadIdx.x & 63;
    if (e >= E) return;
    const int   r = rows[e];
    const int   c = cols[e];
    const float v = vals[e];
    unsigned p = preb2[(size_t)c * (OD / 2) + lane];
    float* o = out + (size_t)r * OD + lane * 2;
    unsafeAtomicAdd(o,     v * __uint_as_float(p << 16));
    unsafeAtomicAdd(o + 1, v * __uint_as_float(p & 0xffff0000u));
}

__global__ __launch_bounds__(256) void bias_relu(float* __restrict__ out,
                                                 const float* __restrict__ b, int n4) {
    int i = blockIdx.x * 256 + threadIdx.x;
    if (i >= n4) return;
    float4 v = reinterpret_cast<float4*>(out)[i];
    int c = (i & ((OD / 4) - 1)) << 2;
    float4 bv = *reinterpret_cast<const float4*>(b + c);
    v.x = fmaxf(v.x + bv.x, 0.f);
    v.y = fmaxf(v.y + bv.y, 0.f);
    v.z = fmaxf(v.z + bv.z, 0.f);
    v.w = fmaxf(v.w + bv.w, 0.f);
    reinterpret_cast<float4*>(out)[i] = v;
}

extern "C" void kernel_launch(void* const* d_in, const int* in_sizes, int n_in,
                              void* d_out, int out_size, void* d_ws, size_t ws_size,
                              hipStream_t stream) {
    const float* x     = (const float*)d_in[0];
    const int*   erows = (const int*)d_in[1];
    const int*   ecols = (const int*)d_in[2];
    const float* evals = (const float*)d_in[3];
    const float* W     = (const float*)d_in[4];
    const float* b     = (const float*)d_in[5];
    float*       out   = (float*)d_out;

    const int M = in_sizes[0] / K_DIM;           // 50000 nodes
    const int E = in_sizes[1];                   // 1.6M edges

    // workspace layout (16B-aligned)
    char* ws = (char*)d_ws;
    size_t off = 0;
    auto alloc = [&](size_t bytes) { char* p = ws + off; off = (off + bytes + 15) & ~(size_t)15; return p; };
    unsigned short* preb    = (unsigned short*)alloc((size_t)M * OD * sizeof(unsigned short)); // 12.8 MB
    int*            cnt     = (int*)  alloc((size_t)M * sizeof(int));
    int*            row_ptr = (int*)  alloc((size_t)(M + 1) * sizeof(int));
    int*            cursor  = (int*)  alloc((size_t)M * sizeof(int));
    int2*           csr     = (int2*) alloc((size_t)E * sizeof(int2));                          // 12.8 MB
    const bool csr_ok = off <= ws_size;

    const int nGemm = (M + 63) / 64;

    if (csr_ok) {
        hipMemsetAsync(cnt, 0, (size_t)M * sizeof(int), stream);
        gemm_hist<<<nGemm + 1024, 256, 0, stream>>>(x, W, preb, erows, cnt, M, E, nGemm);
        scan_rowptr<<<1, 1024, 0, stream>>>(cnt, row_ptr, cursor, M);
        fill_csr<<<(E + 255) / 256, 256, 0, stream>>>(erows, ecols, evals, cursor, csr, E);
        spmm_gather<<<(M * 64 + 255) / 256, 256, 0, stream>>>(row_ptr, csr,
                                                              (const unsigned*)preb, b, out, M);
    } else {
        gemm_hist<<<nGemm, 256, 0, stream>>>(x, W, preb, erows, cnt, M, E, nGemm);
        hipMemsetAsync(d_out, 0, (size_t)out_size * sizeof(float), stream);
        spmm_scatter<<<(E + 3) / 4, 256, 0, stream>>>(erows, ecols, evals,
                                                      (const unsigned*)preb, out, E);
        bias_relu<<<(out_size / 4 + 255) / 256, 256, 0, stream>>>(out, b, out_size / 4);
    }
}

// Round 4
// 273.050 us; speedup vs baseline: 5.0246x; 1.1175x over previous
//
#include <hip/hip_runtime.h>

#define K_DIM 256
#define OD 128

typedef __attribute__((ext_vector_type(8))) short short8;
typedef __attribute__((ext_vector_type(4))) float f32x4;

__device__ inline unsigned short f2bf(float f) {
    unsigned u = __float_as_uint(f);
    unsigned r = (u + 0x7fffu + ((u >> 16) & 1u)) >> 16;   // round-to-nearest-even
    return (unsigned short)r;
}

union Frag8 { short8 s; uint4 u; };

// ---------------- pack W (f32 [256][128]) -> bf16 MFMA B-fragment-linear ----------------
// frag index t = (ks*8 + n)*64 + lane; elem j at k = 32*ks + 4*(l>>4) + (j&3) + 16*(j>>2),
// col = 16*n + (l&15). 16B per frag, coalesced b128 reads in the GEMM.
__global__ __launch_bounds__(256) void pack_w(const float* __restrict__ W,
                                              uint4* __restrict__ wb) {
    int t = blockIdx.x * 256 + threadIdx.x;
    if (t >= 8 * 8 * 64) return;
    int l  = t & 63;
    int n  = (t >> 6) & 7;
    int ks = t >> 9;
    int g  = l >> 4;
    int col = 16 * n + (l & 15);
    int kb  = 32 * ks + 4 * g;
    unsigned short e[8];
    #pragma unroll
    for (int j = 0; j < 8; ++j) {
        int k = kb + (j & 3) + 16 * (j >> 2);
        e[j] = f2bf(W[(size_t)k * OD + col]);
    }
    uint4 u;
    u.x = (unsigned)e[0] | ((unsigned)e[1] << 16);
    u.y = (unsigned)e[2] | ((unsigned)e[3] << 16);
    u.z = (unsigned)e[4] | ((unsigned)e[5] << 16);
    u.w = (unsigned)e[6] | ((unsigned)e[7] << 16);
    wb[t] = u;
}

// ---------------- fused: MFMA GEMM (preb = bf16(x @ W)) + row histogram ----------------
// Blocks [0,nGemm): 64 rows each (4 waves x 16 rows x 128 cols). No LDS, no syncs.
__global__ __launch_bounds__(256) void gemm_hist(const float* __restrict__ x,
                                                 const uint4* __restrict__ wb,
                                                 unsigned short* __restrict__ preb,
                                                 const int* __restrict__ rows,
                                                 int* __restrict__ cnt,
                                                 int M, int E, int nGemm) {
    if ((int)blockIdx.x >= nGemm) {
        int nb  = gridDim.x - nGemm;
        int bid = blockIdx.x - nGemm;
        for (int i = bid * 256 + (int)threadIdx.x; i < E; i += nb * 256)
            atomicAdd(&cnt[rows[i]], 1);
        return;
    }
    const int t = threadIdx.x;
    const int l = t & 63;
    const int w = t >> 6;
    const int g = l >> 4;
    const int row  = blockIdx.x * 64 + w * 16 + (l & 15);
    const int rowc = row < M ? row : M - 1;
    const float* xp = x + (size_t)rowc * K_DIM + g * 4;

    f32x4 acc[8];
    #pragma unroll
    for (int n = 0; n < 8; ++n) acc[n] = (f32x4){0.f, 0.f, 0.f, 0.f};

    #pragma unroll
    for (int ks = 0; ks < 8; ++ks) {
        float4 xa = *reinterpret_cast<const float4*>(xp + 32 * ks);
        float4 xb = *reinterpret_cast<const float4*>(xp + 32 * ks + 16);
        Frag8 a;
        a.u.x = (unsigned)f2bf(xa.x) | ((unsigned)f2bf(xa.y) << 16);
        a.u.y = (unsigned)f2bf(xa.z) | ((unsigned)f2bf(xa.w) << 16);
        a.u.z = (unsigned)f2bf(xb.x) | ((unsigned)f2bf(xb.y) << 16);
        a.u.w = (unsigned)f2bf(xb.z) | ((unsigned)f2bf(xb.w) << 16);
        const uint4* wp = wb + (size_t)ks * 8 * 64 + l;
        #pragma unroll
        for (int n = 0; n < 8; ++n) {
            Frag8 bfrag;
            bfrag.u = wp[n * 64];
            acc[n] = __builtin_amdgcn_mfma_f32_16x16x32_bf16(a.s, bfrag.s, acc[n], 0, 0, 0);
        }
    }
    // C layout: reg r -> row (l>>4)*4 + r, col l&15 (per-tile)
    const int rbase = blockIdx.x * 64 + w * 16 + g * 4;
    #pragma unroll
    for (int r = 0; r < 4; ++r) {
        int ro = rbase + r;
        if (ro < M) {
            unsigned short* dst = preb + (size_t)ro * OD + (l & 15);
            #pragma unroll
            for (int n = 0; n < 8; ++n)
                dst[16 * n] = f2bf(acc[n][r]);
        }
    }
}

// ---------------- scan: row_ptr/cursor = exclusive_scan(cnt), single WG, int4+shfl ----------------
__global__ __launch_bounds__(1024) void scan_rowptr(const int* __restrict__ cnt,
                                                    int* __restrict__ row_ptr,
                                                    int* __restrict__ cursor, int n) {
    __shared__ int wsum[16];
    __shared__ int carry_s;
    const int t = threadIdx.x, lane = t & 63, wid = t >> 6;
    if (t == 0) carry_s = 0;
    __syncthreads();
    for (int base = 0; base < n; base += 4096) {
        int i0 = base + t * 4;
        int v0 = 0, v1 = 0, v2 = 0, v3 = 0;
        if (i0 + 3 < n) {
            int4 v = *reinterpret_cast<const int4*>(cnt + i0);
            v0 = v.x; v1 = v.y; v2 = v.z; v3 = v.w;
        } else {
            if (i0     < n) v0 = cnt[i0];
            if (i0 + 1 < n) v1 = cnt[i0 + 1];
            if (i0 + 2 < n) v2 = cnt[i0 + 2];
            if (i0 + 3 < n) v3 = cnt[i0 + 3];
        }
        int s  = v0 + v1 + v2 + v3;
        int sc = s;
        #pragma unroll
        for (int off = 1; off < 64; off <<= 1) {
            int u = __shfl_up(sc, off, 64);
            if (lane >= off) sc += u;
        }
        if (lane == 63) wsum[wid] = sc;
        __syncthreads();
        if (wid == 0) {
            int wv  = (lane < 16) ? wsum[lane] : 0;
            int wsc = wv;
            #pragma unroll
            for (int off = 1; off < 16; off <<= 1) {
                int u = __shfl_up(wsc, off, 64);
                if (lane >= off) wsc += u;
            }
            if (lane < 16) wsum[lane] = wsc - wv;
        }
        __syncthreads();
        int excl = carry_s + wsum[wid] + (sc - s);
        int p0 = excl, p1 = p0 + v0, p2 = p1 + v1, p3 = p2 + v2;
        if (i0 + 3 < n) {
            *reinterpret_cast<int4*>(row_ptr + i0) = make_int4(p0, p1, p2, p3);
            *reinterpret_cast<int4*>(cursor  + i0) = make_int4(p0, p1, p2, p3);
        } else {
            if (i0     < n) { row_ptr[i0]     = p0; cursor[i0]     = p0; }
            if (i0 + 1 < n) { row_ptr[i0 + 1] = p1; cursor[i0 + 1] = p1; }
            if (i0 + 2 < n) { row_ptr[i0 + 2] = p2; cursor[i0 + 2] = p2; }
            if (i0 + 3 < n) { row_ptr[i0 + 3] = p3; cursor[i0 + 3] = p3; }
        }
        __syncthreads();
        if (t == 1023) carry_s += wsum[15] + sc;
        __syncthreads();
    }
    if (t == 0) row_ptr[n] = carry_s;
}

// ---------------- fill: csr[pos] = {col, val_bits}, single 8B store per edge ----------------
__global__ __launch_bounds__(256) void fill_csr(const int* __restrict__ rows,
                                                const int* __restrict__ cols,
                                                const float* __restrict__ vals,
                                                int* __restrict__ cursor,
                                                int2* __restrict__ csr, int E) {
    int i = blockIdx.x * 256 + threadIdx.x;
    if (i >= E) return;
    int pos = atomicAdd(&cursor[rows[i]], 1);
    csr[pos] = make_int2(cols[i], __float_as_int(vals[i]));
}

// ---------------- gather: out[r] = relu(b + sum val * pre_bf16[col]) ----------------
__global__ __launch_bounds__(256) void spmm_gather(const int* __restrict__ row_ptr,
                                                   const int2* __restrict__ csr,
                                                   const unsigned* __restrict__ preb2,
                                                   const float* __restrict__ b,
                                                   float* __restrict__ out, int n) {
    const int w    = (int)((blockIdx.x * 256u + threadIdx.x) >> 6);
    const int lane = threadIdx.x & 63;
    if (w >= n) return;
    const int beg = row_ptr[w];
    const int end = row_ptr[w + 1];
    float ax = 0.f, ay = 0.f;
    int j = beg;
    for (; j + 4 <= end; j += 4) {
        int2 e0 = csr[j], e1 = csr[j + 1], e2 = csr[j + 2], e3 = csr[j + 3];
        unsigned p0 = preb2[(size_t)e0.x * (OD / 2) + lane];
        unsigned p1 = preb2[(size_t)e1.x * (OD / 2) + lane];
        unsigned p2 = preb2[(size_t)e2.x * (OD / 2) + lane];
        unsigned p3 = preb2[(size_t)e3.x * (OD / 2) + lane];
        float v0 = __int_as_float(e0.y), v1 = __int_as_float(e1.y);
        float v2 = __int_as_float(e2.y), v3 = __int_as_float(e3.y);
        ax = fmaf(v0, __uint_as_float(p0 << 16), ax);
        ay = fmaf(v0, __uint_as_float(p0 & 0xffff0000u), ay);
        ax = fmaf(v1, __uint_as_float(p1 << 16), ax);
        ay = fmaf(v1, __uint_as_float(p1 & 0xffff0000u), ay);
        ax = fmaf(v2, __uint_as_float(p2 << 16), ax);
        ay = fmaf(v2, __uint_as_float(p2 & 0xffff0000u), ay);
        ax = fmaf(v3, __uint_as_float(p3 << 16), ax);
        ay = fmaf(v3, __uint_as_float(p3 & 0xffff0000u), ay);
    }
    for (; j < end; ++j) {
        int2 e = csr[j];
        unsigned p = preb2[(size_t)e.x * (OD / 2) + lane];
        float v = __int_as_float(e.y);
        ax = fmaf(v, __uint_as_float(p << 16), ax);
        ay = fmaf(v, __uint_as_float(p & 0xffff0000u), ay);
    }
    float2 bv = *reinterpret_cast<const float2*>(b + lane * 2);
    float2 o;
    o.x = fmaxf(ax + bv.x, 0.f);
    o.y = fmaxf(ay + bv.y, 0.f);
    *reinterpret_cast<float2*>(out + (size_t)w * OD + lane * 2) = o;
}

// ---------------- fallback (tiny ws): atomic scatter over bf16 pre ----------------
__global__ __launch_bounds__(256) void spmm_scatter(const int* __restrict__ rows,
                                                    const int* __restrict__ cols,
                                                    const float* __restrict__ vals,
                                                    const unsigned* __restrict__ preb2,
                                                    float* __restrict__ out, int E) {
    const int e    = (int)((blockIdx.x * 256u + threadIdx.x) >> 6);
    const int lane = threadIdx.x & 63;
    if (e >= E) return;
    const int   r = rows[e];
    const int   c = cols[e];
    const float v = vals[e];
    unsigned p = preb2[(size_t)c * (OD / 2) + lane];
    float* o = out + (size_t)r * OD + lane * 2;
    unsafeAtomicAdd(o,     v * __uint_as_float(p << 16));
    unsafeAtomicAdd(o + 1, v * __uint_as_float(p & 0xffff0000u));
}

__global__ __launch_bounds__(256) void bias_relu(float* __restrict__ out,
                                                 const float* __restrict__ b, int n4) {
    int i = blockIdx.x * 256 + threadIdx.x;
    if (i >= n4) return;
    float4 v = reinterpret_cast<float4*>(out)[i];
    int c = (i & ((OD / 4) - 1)) << 2;
    float4 bv = *reinterpret_cast<const float4*>(b + c);
    v.x = fmaxf(v.x + bv.x, 0.f);
    v.y = fmaxf(v.y + bv.y, 0.f);
    v.z = fmaxf(v.z + bv.z, 0.f);
    v.w = fmaxf(v.w + bv.w, 0.f);
    reinterpret_cast<float4*>(out)[i] = v;
}

extern "C" void kernel_launch(void* const* d_in, const int* in_sizes, int n_in,
                              void* d_out, int out_size, void* d_ws, size_t ws_size,
                              hipStream_t stream) {
    const float* x     = (const float*)d_in[0];
    const int*   erows = (const int*)d_in[1];
    const int*   ecols = (const int*)d_in[2];
    const float* evals = (const float*)d_in[3];
    const float* W     = (const float*)d_in[4];
    const float* b     = (const float*)d_in[5];
    float*       out   = (float*)d_out;

    const int M = in_sizes[0] / K_DIM;           // 50000 nodes
    const int E = in_sizes[1];                   // 1.6M edges

    // workspace layout (16B-aligned)
    char* ws = (char*)d_ws;
    size_t off = 0;
    auto alloc = [&](size_t bytes) { char* p = ws + off; off = (off + bytes + 15) & ~(size_t)15; return p; };
    unsigned short* preb    = (unsigned short*)alloc((size_t)M * OD * sizeof(unsigned short)); // 12.8 MB
    uint4*          wb      = (uint4*)alloc((size_t)8 * 8 * 64 * sizeof(uint4));               // 64 KB
    int*            cnt     = (int*)  alloc((size_t)M * sizeof(int));
    int*            row_ptr = (int*)  alloc((size_t)(M + 1) * sizeof(int));
    int*            cursor  = (int*)  alloc((size_t)M * sizeof(int));
    int2*           csr     = (int2*) alloc((size_t)E * sizeof(int2));                          // 12.8 MB
    const bool csr_ok = off <= ws_size;

    const int nGemm = (M + 63) / 64;

    pack_w<<<16, 256, 0, stream>>>(W, wb);

    if (csr_ok) {
        hipMemsetAsync(cnt, 0, (size_t)M * sizeof(int), stream);
        gemm_hist<<<nGemm + 1024, 256, 0, stream>>>(x, wb, preb, erows, cnt, M, E, nGemm);
        scan_rowptr<<<1, 1024, 0, stream>>>(cnt, row_ptr, cursor, M);
        fill_csr<<<(E + 255) / 256, 256, 0, stream>>>(erows, ecols, evals, cursor, csr, E);
        spmm_gather<<<(M * 64 + 255) / 256, 256, 0, stream>>>(row_ptr, csr,
                                                              (const unsigned*)preb, b, out, M);
    } else {
        gemm_hist<<<nGemm, 256, 0, stream>>>(x, wb, preb, erows, cnt, M, E, nGemm);
        hipMemsetAsync(d_out, 0, (size_t)out_size * sizeof(float), stream);
        spmm_scatter<<<(E + 3) / 4, 256, 0, stream>>>(erows, ecols, evals,
                                                      (const unsigned*)preb, out, E);
        bias_relu<<<(out_size / 4 + 255) / 256, 256, 0, stream>>>(out, b, out_size / 4);
    }
}